// Round 1
// baseline (367563.037 us; speedup 1.0000x reference)
//
#include <hip/hip_runtime.h>
#include <stdint.h>

// Problem dims
#define T_STEPS 8192
#define DIN     2048
#define HD      2048
#define G3      6144
#define EOUT    512

// Scan partition: 64 A-workgroups own r (32 cols each),
// 128 B-workgroups own z+a+h' (16 cols each of Wz and Wa).
#define NA 64
#define NB 128
#define SPIN_MAX (1<<21)

__device__ __forceinline__ float bf_lo(uint32_t u){ return __uint_as_float(u << 16); }
__device__ __forceinline__ float bf_hi(uint32_t u){ return __uint_as_float(u & 0xffff0000u); }

__device__ __forceinline__ uint16_t f2bf(float v){   // RNE f32->bf16
  uint32_t x = __float_as_uint(v);
  return (uint16_t)((x + 0x7fffu + ((x >> 16) & 1u)) >> 16);
}

// Pack a 2048 x NCOLS column slice of w_h (f32, row-major stride G3) into LDS
// in exact per-lane access order for matvec16:
//   uint16 idx = w4*8192 + it*512 + (c*4+j)*8 + m
//   where col_local = 4*w4 + j, k = c*128 + it*8 + m.
template<int NCOLS>
__device__ void pack_w(uint16_t* dst, const float* __restrict__ wsrc, int col0, int tid){
  for (int idx = tid; idx < HD*NCOLS; idx += 512){
    int k  = idx / NCOLS;
    int cl = idx & (NCOLS - 1);
    uint16_t u = f2bf(wsrc[(size_t)k*G3 + col0 + cl]);
    int w4 = cl >> 2, j = cl & 3, c = k >> 7, it = (k & 127) >> 3, m = k & 7;
    dst[w4*8192 + it*512 + (c*4 + j)*8 + m] = u;
  }
}

// One wave computes 4 columns x 2048 rows: lane j=lane&3 owns a column,
// c=lane>>2 picks the 128-row chunk. Input vector is staged in LDS with
// chunk-padded layout: element k at (k>>7)*132 + (k&127)  (bank-safe).
__device__ __forceinline__ float matvec16(const uint16_t* Wp, const float* in_lds, int w4, int lane){
  const int c = lane >> 2;
  const uint4* wb = (const uint4*)(Wp + (size_t)w4*8192);
  const float* hb = in_lds + c*132;
  float acc = 0.f;
  #pragma unroll
  for (int it = 0; it < 16; ++it){
    uint4  w  = wb[it*64 + lane];                    // 8 bf16, ds_read_b128, conflict-free
    float4 h0 = *(const float4*)(hb + it*8);
    float4 h1 = *(const float4*)(hb + it*8 + 4);
    acc = fmaf(bf_lo(w.x), h0.x, acc);
    acc = fmaf(bf_hi(w.x), h0.y, acc);
    acc = fmaf(bf_lo(w.y), h0.z, acc);
    acc = fmaf(bf_hi(w.y), h0.w, acc);
    acc = fmaf(bf_lo(w.z), h1.x, acc);
    acc = fmaf(bf_hi(w.z), h1.y, acc);
    acc = fmaf(bf_lo(w.w), h1.z, acc);
    acc = fmaf(bf_hi(w.w), h1.w, acc);
  }
  acc += __shfl_xor(acc, 4, 64);
  acc += __shfl_xor(acc, 8, 64);
  acc += __shfl_xor(acc, 16, 64);
  acc += __shfl_xor(acc, 32, 64);
  return acc;   // every lane holds the total for its column j=lane&3
}

// Spin until all flags >= target. flags read pairwise as u64; npairs is pow2.
__device__ __forceinline__ bool poll_ge(const int* flags, int npairs, int target, int lane){
  int idx = lane & (npairs - 1);
  int spins = 0;
  for(;;){
    unsigned long long pr = __hip_atomic_load((const unsigned long long*)flags + idx,
                                              __ATOMIC_RELAXED, __HIP_MEMORY_SCOPE_AGENT);
    int a = (int)(uint32_t)(pr & 0xffffffffull);
    int b = (int)(uint32_t)(pr >> 32);
    if (__all(a >= target && b >= target)) return true;
    if (++spins > SPIN_MAX) return false;   // bailout instead of deadlock
    __builtin_amdgcn_s_sleep(4);
  }
}

// Coherent (agent-scope) 8B loads of a 2048-f32 vector -> chunk-padded LDS.
__device__ __forceinline__ void load_vec(const float* __restrict__ gsrc, float* dst, int tid, int nthr){
  for (int p = tid; p < HD/2; p += nthr){
    unsigned long long v = __hip_atomic_load((const unsigned long long*)gsrc + p,
                                             __ATOMIC_RELAXED, __HIP_MEMORY_SCOPE_AGENT);
    union { unsigned long long u; float2 f; } cv; cv.u = v;
    int col = 2*p;
    *(float2*)(dst + (col >> 7)*132 + (col & 127)) = cv.f;
  }
}

// ---------------- gates GEMM: C[T,6144] = X[T,2048] @ Wi[2048,6144], fp32 ----
__global__ __launch_bounds__(256) void gates_gemm(const float* __restrict__ A,
                                                  const float* __restrict__ B,
                                                  float* __restrict__ C){
  __shared__ float As[16*132];   // A^T tile: [k][row], stride 132
  __shared__ float Bs[16*132];   // B tile:   [k][col], stride 132
  const int bm = blockIdx.x / (G3/128);
  const int bn = blockIdx.x % (G3/128);
  const int row0 = bm*128, col0 = bn*128;
  const int tid = threadIdx.x;
  const int tr = tid >> 4, tc = tid & 15;
  float acc[8][8] = {};
  for (int k0 = 0; k0 < DIN; k0 += 16){
    {
      int r = tid >> 4, c = tid & 15;
      #pragma unroll
      for (int i = 0; i < 8; ++i){
        int row = r + 16*i;
        As[c*132 + row] = A[(size_t)(row0 + row)*DIN + k0 + c];
      }
    }
    {
      int kk = tid >> 7, cc = tid & 127;
      #pragma unroll
      for (int i = 0; i < 8; ++i){
        int k = kk + 2*i;
        Bs[k*132 + cc] = B[(size_t)(k0 + k)*G3 + col0 + cc];
      }
    }
    __syncthreads();
    #pragma unroll
    for (int kk = 0; kk < 16; ++kk){
      float4 a0 = *(float4*)&As[kk*132 + 8*tr];
      float4 a1 = *(float4*)&As[kk*132 + 8*tr + 4];
      float4 b0 = *(float4*)&Bs[kk*132 + 8*tc];
      float4 b1 = *(float4*)&Bs[kk*132 + 8*tc + 4];
      float av[8] = {a0.x,a0.y,a0.z,a0.w,a1.x,a1.y,a1.z,a1.w};
      float bv[8] = {b0.x,b0.y,b0.z,b0.w,b1.x,b1.y,b1.z,b1.w};
      #pragma unroll
      for (int i = 0; i < 8; ++i)
        #pragma unroll
        for (int j = 0; j < 8; ++j)
          acc[i][j] = fmaf(av[i], bv[j], acc[i][j]);
    }
    __syncthreads();
  }
  #pragma unroll
  for (int i = 0; i < 8; ++i){
    size_t off = (size_t)(row0 + 8*tr + i)*G3 + col0 + 8*tc;
    float4 v0 = {acc[i][0],acc[i][1],acc[i][2],acc[i][3]};
    float4 v1 = {acc[i][4],acc[i][5],acc[i][6],acc[i][7]};
    *(float4*)(C + off)     = v0;
    *(float4*)(C + off + 4) = v1;
  }
}

// ---------------- persistent GRU scan --------------------------------------
__global__ __launch_bounds__(512) void scan_kernel(
    const float* __restrict__ gates, const float* __restrict__ w_h,
    const float* __restrict__ b,
    float* hbuf, float* rhbuf, int* flagA, int* flagB)
{
  __shared__ __align__(16) unsigned char smem[148352];
  uint16_t* W0     = (uint16_t*)(smem);            // A: Wr (128KB). B: Wz (64KB)
  uint16_t* W1     = (uint16_t*)(smem + 65536);    // B: Wa (64KB)
  float*    h_lds  = (float*)(smem + 131072);      // 16*132 f32
  float*    rh_lds = (float*)(smem + 139520);      // 16*132 f32
  float*    gx_lds = (float*)(smem + 147968);      // 2 x 32 f32 (bias folded in)
  float*    zbuf   = (float*)(smem + 148224);      // 16 f32
  volatile int* deadp = (volatile int*)(smem + 148288);

  const int tid  = threadIdx.x;
  const int lane = tid & 63;
  const int wid  = tid >> 6;
  const bool isA = blockIdx.x < NA;
  const int  g   = isA ? (int)blockIdx.x : (int)blockIdx.x - NA;

  if (isA) {
    pack_w<32>(W0, w_h, 2048 + 32*g, tid);                 // r columns
  } else {
    pack_w<16>(W0, w_h, 16*g, tid);                        // z columns
    pack_w<16>(W1, w_h, 4096 + 16*g, tid);                 // a columns
  }
  if (tid == 0) *deadp = 0;

  int   gcol = -1;
  float bias = 0.f;
  if (isA) { if (tid < 32) gcol = 2048 + 32*g + tid; }
  else     { if (tid < 16) gcol = 16*g + tid;
             else if (tid < 32) gcol = 4096 + 16*g + (tid - 16); }
  if (gcol >= 0) { bias = b[gcol]; gx_lds[tid & 31] = gates[gcol] + bias; }
  __syncthreads();

  for (int t = 0; t < T_STEPS; ++t){
    const int par = t & 1;
    float gxn = 0.f;                                       // prefetch next step's x-gates
    if (gcol >= 0){
      int tn = (t + 1 < T_STEPS) ? t + 1 : t;
      gxn = gates[(size_t)tn*G3 + gcol] + bias;
    }
    if (!poll_ge(flagB, 64, t, lane)) { if (lane == 0) *deadp = 1; }
    __threadfence();
    __syncthreads();
    if (*deadp) break;
    load_vec(hbuf + (size_t)par*HD, h_lds, tid, 512);      // H_t -> LDS
    __syncthreads();

    if (isA) {
      float acc = matvec16(W0, h_lds, wid, lane);          // r pre-activation
      if (lane < 4){
        int cl = 4*wid + lane;
        float pre = acc + gx_lds[par*32 + cl];
        float r = 1.f / (1.f + __expf(-pre));
        int col = 32*g + cl;
        float rh = r * h_lds[(col >> 7)*132 + (col & 127)];
        __hip_atomic_store((unsigned int*)rhbuf + (size_t)par*HD + col,
                           __float_as_uint(rh), __ATOMIC_RELAXED, __HIP_MEMORY_SCOPE_AGENT);
      }
      if (gcol >= 0) gx_lds[((t+1)&1)*32 + (tid & 31)] = gxn;
      __syncthreads();                                     // drain stores
      if (tid == 0) __hip_atomic_store(flagA + g, t + 1, __ATOMIC_RELEASE, __HIP_MEMORY_SCOPE_AGENT);
    } else {
      if (wid < 4){                                        // z while rh is in flight
        float acc = matvec16(W0, h_lds, wid, lane);
        if (lane < 4){
          int cl = 4*wid + lane;
          float pre = acc + gx_lds[par*32 + cl];
          zbuf[cl] = 1.f / (1.f + __expf(-pre));
        }
      } else {
        if (!poll_ge(flagA, 32, t + 1, lane)) { if (lane == 0) *deadp = 1; }
        __threadfence();
        load_vec(rhbuf + (size_t)par*HD, rh_lds, tid - 256, 256);
      }
      __syncthreads();
      if (*deadp) break;
      if (wid >= 4){
        float acc = matvec16(W1, rh_lds, wid - 4, lane);   // a pre-activation
        if (lane < 4){
          int cl = 4*(wid - 4) + lane;
          float a = tanhf(acc + gx_lds[par*32 + 16 + cl]);
          float z = zbuf[cl];
          int col = 16*g + cl;
          float hold = h_lds[(col >> 7)*132 + (col & 127)];
          float hnew = hold + z*(a - hold);                // (1-z)h + z*a
          __hip_atomic_store((unsigned int*)hbuf + (size_t)((t+1)&1)*HD + col,
                             __float_as_uint(hnew), __ATOMIC_RELAXED, __HIP_MEMORY_SCOPE_AGENT);
        }
      }
      if (gcol >= 0) gx_lds[((t+1)&1)*32 + (tid & 31)] = gxn;
      __syncthreads();
      if (tid == 0) __hip_atomic_store(flagB + g, t + 1, __ATOMIC_RELEASE, __HIP_MEMORY_SCOPE_AGENT);
    }
  }
}

// ---------------- out = h_final @ w_out + b_out ----------------------------
__global__ __launch_bounds__(1024) void out_proj(const float* __restrict__ hfin,
                                                 const float* __restrict__ w_out,
                                                 const float* __restrict__ b_out,
                                                 float* __restrict__ out){
  __shared__ float red[16][80];
  const int g  = blockIdx.x;
  const int cl = threadIdx.x & 63;
  const int kc = threadIdx.x >> 6;        // 0..15
  const int col = 64*g + cl;
  float acc = 0.f;
  for (int k = kc*128; k < kc*128 + 128; ++k)
    acc = fmaf(hfin[k], w_out[(size_t)k*EOUT + col], acc);
  red[kc][cl] = acc;
  __syncthreads();
  if (kc == 0){
    float s = 0.f;
    #pragma unroll
    for (int q = 0; q < 16; ++q) s += red[q][cl];
    out[col] = s + b_out[col];
  }
}

extern "C" void kernel_launch(void* const* d_in, const int* in_sizes, int n_in,
                              void* d_out, int out_size, void* d_ws, size_t ws_size,
                              hipStream_t stream) {
  const float* x     = (const float*)d_in[0];   // (8192, 2048)
  const float* w_i   = (const float*)d_in[1];   // (2048, 6144)
  const float* w_h   = (const float*)d_in[2];   // (2048, 6144)
  const float* b     = (const float*)d_in[3];   // (6144,)
  const float* w_out = (const float*)d_in[4];   // (2048, 512)
  const float* b_out = (const float*)d_in[5];   // (512,)
  float* out = (float*)d_out;

  // Workspace layout: gates f32 (201.3MB) | hbuf[2][2048] | rhbuf[2][2048] | flagA[64] | flagB[128]
  float* gates = (float*)d_ws;
  float* hbuf  = gates + (size_t)T_STEPS * G3;
  float* rhbuf = hbuf + 2*HD;
  int*   flagA = (int*)(rhbuf + 2*HD);
  int*   flagB = flagA + 64;
  (void)in_sizes; (void)n_in; (void)out_size; (void)ws_size;

  // zero h0 + rh + flags (in-stream, graph-capturable)
  hipMemsetAsync(hbuf, 0, (size_t)(2*HD + 2*HD)*sizeof(float) + 192*sizeof(int), stream);

  gates_gemm<<<dim3((T_STEPS/128)*(G3/128)), dim3(256), 0, stream>>>(x, w_i, gates);

  const float* gates_c = gates;
  void* kargs[7];
  kargs[0] = (void*)&gates_c;
  kargs[1] = (void*)&w_h;
  kargs[2] = (void*)&b;
  kargs[3] = (void*)&hbuf;
  kargs[4] = (void*)&rhbuf;
  kargs[5] = (void*)&flagA;
  kargs[6] = (void*)&flagB;
  hipLaunchCooperativeKernel((void*)scan_kernel, dim3(NA + NB), dim3(512), kargs, 0u, stream);

  // T even -> final h in hbuf[0]
  out_proj<<<dim3(EOUT/64), dim3(1024), 0, stream>>>(hbuf, w_out, b_out, out);
}

// Round 2
// 53474.945 us; speedup vs baseline: 6.8736x; 6.8736x over previous
//
#include <hip/hip_runtime.h>
#include <stdint.h>

// Problem dims
#define T_STEPS 8192
#define DIN     2048
#define HD      2048
#define G3      6144
#define EOUT    512

// Scan partition: 64 A-workgroups own r (32 cols each),
// 128 B-workgroups own z+a+h' (16 cols each of Wz and Wa).
#define NA 64
#define NB 128
#define SPIN_MAX (1<<22)
#define FSTRIDE 32   // flag padding: 32 ints = 128B per flag (own cache line)

__device__ __forceinline__ float bf_lo(uint32_t u){ return __uint_as_float(u << 16); }
__device__ __forceinline__ float bf_hi(uint32_t u){ return __uint_as_float(u & 0xffff0000u); }

__device__ __forceinline__ uint16_t f2bf(float v){   // RNE f32->bf16
  uint32_t x = __float_as_uint(v);
  return (uint16_t)((x + 0x7fffu + ((x >> 16) & 1u)) >> 16);
}

// Pack a 2048 x NCOLS column slice of w_h (f32, row-major stride G3) into LDS
// in exact per-lane access order for matvec16:
//   uint16 idx = w4*8192 + it*512 + (c*4+j)*8 + m
//   where col_local = 4*w4 + j, k = c*128 + it*8 + m.
template<int NCOLS>
__device__ void pack_w(uint16_t* dst, const float* __restrict__ wsrc, int col0, int tid){
  for (int idx = tid; idx < HD*NCOLS; idx += 512){
    int k  = idx / NCOLS;
    int cl = idx & (NCOLS - 1);
    uint16_t u = f2bf(wsrc[(size_t)k*G3 + col0 + cl]);
    int w4 = cl >> 2, j = cl & 3, c = k >> 7, it = (k & 127) >> 3, m = k & 7;
    dst[w4*8192 + it*512 + (c*4 + j)*8 + m] = u;
  }
}

// One wave computes 4 columns x 2048 rows: lane j=lane&3 owns a column,
// c=lane>>2 picks the 128-row chunk. Input vector is staged in LDS with
// chunk-padded layout: element k at (k>>7)*132 + (k&127)  (bank-safe, 16B-aligned).
__device__ __forceinline__ float matvec16(const uint16_t* Wp, const float* in_lds, int w4, int lane){
  const int c = lane >> 2;
  const uint4* wb = (const uint4*)(Wp + (size_t)w4*8192);
  const float* hb = in_lds + c*132;
  float acc = 0.f;
  #pragma unroll
  for (int it = 0; it < 16; ++it){
    uint4  w  = wb[it*64 + lane];                    // 8 bf16, ds_read_b128, conflict-free
    float4 h0 = *(const float4*)(hb + it*8);
    float4 h1 = *(const float4*)(hb + it*8 + 4);
    acc = fmaf(bf_lo(w.x), h0.x, acc);
    acc = fmaf(bf_hi(w.x), h0.y, acc);
    acc = fmaf(bf_lo(w.y), h0.z, acc);
    acc = fmaf(bf_hi(w.y), h0.w, acc);
    acc = fmaf(bf_lo(w.z), h1.x, acc);
    acc = fmaf(bf_hi(w.z), h1.y, acc);
    acc = fmaf(bf_lo(w.w), h1.z, acc);
    acc = fmaf(bf_hi(w.w), h1.w, acc);
  }
  acc += __shfl_xor(acc, 4, 64);
  acc += __shfl_xor(acc, 8, 64);
  acc += __shfl_xor(acc, 16, 64);
  acc += __shfl_xor(acc, 32, 64);
  return acc;   // every lane holds the total for its column j=lane&3
}

// Spin until all N padded flags >= target. N is 64 or 128.
template<int N>
__device__ __forceinline__ bool poll_all(const int* flags, int target, int lane){
  int spins = 0;
  for(;;){
    int ok = 1;
    #pragma unroll
    for (int i = 0; i < N; i += 64){
      int v = __hip_atomic_load(flags + (size_t)(i + lane)*FSTRIDE,
                                __ATOMIC_RELAXED, __HIP_MEMORY_SCOPE_AGENT);
      ok &= (v >= target);
    }
    if (__all(ok)) return true;
    if (++spins > SPIN_MAX) return false;   // bailout instead of deadlock
    __builtin_amdgcn_s_sleep(1);
  }
}

// Coherent (agent-scope) 8B loads of a 2048-f32 vector -> chunk-padded LDS.
__device__ __forceinline__ void load_vec(const float* __restrict__ gsrc, float* dst, int tid, int nthr){
  for (int p = tid; p < HD/2; p += nthr){
    unsigned long long v = __hip_atomic_load((const unsigned long long*)gsrc + p,
                                             __ATOMIC_RELAXED, __HIP_MEMORY_SCOPE_AGENT);
    union { unsigned long long u; float2 f; } cv; cv.u = v;
    int col = 2*p;
    *(float2*)(dst + (col >> 7)*132 + (col & 127)) = cv.f;
  }
}

// ---------------- gates GEMM: C[T,6144] = X[T,2048] @ Wi[2048,6144], fp32 ----
__global__ __launch_bounds__(256) void gates_gemm(const float* __restrict__ A,
                                                  const float* __restrict__ B,
                                                  float* __restrict__ C){
  __shared__ float As[16*132];   // A^T tile: [k][row], stride 132
  __shared__ float Bs[16*132];   // B tile:   [k][col], stride 132
  const int bm = blockIdx.x / (G3/128);
  const int bn = blockIdx.x % (G3/128);
  const int row0 = bm*128, col0 = bn*128;
  const int tid = threadIdx.x;
  const int tr = tid >> 4, tc = tid & 15;
  float acc[8][8] = {};
  for (int k0 = 0; k0 < DIN; k0 += 16){
    {
      int r = tid >> 4, c = tid & 15;
      #pragma unroll
      for (int i = 0; i < 8; ++i){
        int row = r + 16*i;
        As[c*132 + row] = A[(size_t)(row0 + row)*DIN + k0 + c];
      }
    }
    {
      int kk = tid >> 7, cc = tid & 127;
      #pragma unroll
      for (int i = 0; i < 8; ++i){
        int k = kk + 2*i;
        Bs[k*132 + cc] = B[(size_t)(k0 + k)*G3 + col0 + cc];
      }
    }
    __syncthreads();
    #pragma unroll
    for (int kk = 0; kk < 16; ++kk){
      float4 a0 = *(float4*)&As[kk*132 + 8*tr];
      float4 a1 = *(float4*)&As[kk*132 + 8*tr + 4];
      float4 b0 = *(float4*)&Bs[kk*132 + 8*tc];
      float4 b1 = *(float4*)&Bs[kk*132 + 8*tc + 4];
      float av[8] = {a0.x,a0.y,a0.z,a0.w,a1.x,a1.y,a1.z,a1.w};
      float bv[8] = {b0.x,b0.y,b0.z,b0.w,b1.x,b1.y,b1.z,b1.w};
      #pragma unroll
      for (int i = 0; i < 8; ++i)
        #pragma unroll
        for (int j = 0; j < 8; ++j)
          acc[i][j] = fmaf(av[i], bv[j], acc[i][j]);
    }
    __syncthreads();
  }
  #pragma unroll
  for (int i = 0; i < 8; ++i){
    size_t off = (size_t)(row0 + 8*tr + i)*G3 + col0 + 8*tc;
    float4 v0 = {acc[i][0],acc[i][1],acc[i][2],acc[i][3]};
    float4 v1 = {acc[i][4],acc[i][5],acc[i][6],acc[i][7]};
    *(float4*)(C + off)     = v0;
    *(float4*)(C + off + 4) = v1;
  }
}

// ---------------- persistent GRU scan --------------------------------------
// Sync protocol (no fences, no release/acquire — all cross-block data moves
// via agent-scope atomics which are LLC-coherent by themselves):
//   producer: data stores (atomic relaxed agent) -> __syncthreads() [drains
//   vmcnt(0) per wave, so stores are LLC-visible] -> tid0 relaxed flag store.
//   consumer: poll flag (relaxed agent) -> data loads are control-dependent
//   on the poll, so they are issued after the flag value is observed.
__global__ __launch_bounds__(512) void scan_kernel(
    const float* __restrict__ gates, const float* __restrict__ w_h,
    const float* __restrict__ b,
    float* hbuf, float* rhbuf, int* flagA, int* flagB)
{
  __shared__ __align__(16) unsigned char smem[148352];
  uint16_t* W0     = (uint16_t*)(smem);            // A: Wr (128KB). B: Wz (64KB)
  uint16_t* W1     = (uint16_t*)(smem + 65536);    // B: Wa (64KB)
  float*    h_lds  = (float*)(smem + 131072);      // 16*132 f32
  float*    rh_lds = (float*)(smem + 139520);      // 16*132 f32
  float*    gx_lds = (float*)(smem + 147968);      // 2 x 32 f32 (bias folded in)
  float*    zbuf   = (float*)(smem + 148224);      // 16 f32
  volatile int* deadp = (volatile int*)(smem + 148288);

  const int tid  = threadIdx.x;
  const int lane = tid & 63;
  const int wid  = tid >> 6;
  const bool isA = blockIdx.x < NA;
  const int  g   = isA ? (int)blockIdx.x : (int)blockIdx.x - NA;

  if (isA) {
    pack_w<32>(W0, w_h, 2048 + 32*g, tid);                 // r columns
  } else {
    pack_w<16>(W0, w_h, 16*g, tid);                        // z columns
    pack_w<16>(W1, w_h, 4096 + 16*g, tid);                 // a columns
  }
  if (tid == 0) *deadp = 0;

  int   gcol = -1;
  float bias = 0.f;
  if (isA) { if (tid < 32) gcol = 2048 + 32*g + tid; }
  else     { if (tid < 16) gcol = 16*g + tid;
             else if (tid < 32) gcol = 4096 + 16*g + (tid - 16); }
  if (gcol >= 0) { bias = b[gcol]; gx_lds[tid & 31] = gates[gcol] + bias; }
  __syncthreads();

  for (int t = 0; t < T_STEPS; ++t){
    const int par = t & 1;
    float gxn = 0.f;                                       // prefetch next step's x-gates
    if (gcol >= 0){
      int tn = (t + 1 < T_STEPS) ? t + 1 : t;
      gxn = gates[(size_t)tn*G3 + gcol] + bias;
    }
    if (wid == 0){                                         // only wave 0 polls H-ready
      if (!poll_all<NB>(flagB, t, lane) && lane == 0) *deadp = 1;
    }
    __syncthreads();
    if (*deadp) break;
    load_vec(hbuf + (size_t)par*HD, h_lds, tid, 512);      // H_t -> LDS
    __syncthreads();

    if (isA) {
      float acc = matvec16(W0, h_lds, wid, lane);          // r pre-activation
      if (lane < 4){
        int cl = 4*wid + lane;
        float pre = acc + gx_lds[par*32 + cl];
        float r = 1.f / (1.f + __expf(-pre));
        int col = 32*g + cl;
        float rh = r * h_lds[(col >> 7)*132 + (col & 127)];
        __hip_atomic_store((unsigned int*)rhbuf + (size_t)par*HD + col,
                           __float_as_uint(rh), __ATOMIC_RELAXED, __HIP_MEMORY_SCOPE_AGENT);
      }
      if (gcol >= 0) gx_lds[((t+1)&1)*32 + (tid & 31)] = gxn;
      __syncthreads();                                     // drains vmcnt -> rh visible
      if (tid == 0) __hip_atomic_store(flagA + (size_t)g*FSTRIDE, t + 1,
                                       __ATOMIC_RELAXED, __HIP_MEMORY_SCOPE_AGENT);
    } else {
      if (wid < 4){                                        // z while rh is in flight
        float acc = matvec16(W0, h_lds, wid, lane);
        if (lane < 4){
          int cl = 4*wid + lane;
          float pre = acc + gx_lds[par*32 + cl];
          zbuf[cl] = 1.f / (1.f + __expf(-pre));
        }
      } else {
        if (!poll_all<NA>(flagA, t + 1, lane) && lane == 0) *deadp = 1;
        load_vec(rhbuf + (size_t)par*HD, rh_lds, tid - 256, 256);
      }
      __syncthreads();
      if (*deadp) break;
      if (wid >= 4){
        float acc = matvec16(W1, rh_lds, wid - 4, lane);   // a pre-activation
        if (lane < 4){
          int cl = 4*(wid - 4) + lane;
          float a = tanhf(acc + gx_lds[par*32 + 16 + cl]);
          float z = zbuf[cl];
          int col = 16*g + cl;
          float hold = h_lds[(col >> 7)*132 + (col & 127)];
          float hnew = hold + z*(a - hold);                // (1-z)h + z*a
          __hip_atomic_store((unsigned int*)hbuf + (size_t)((t+1)&1)*HD + col,
                             __float_as_uint(hnew), __ATOMIC_RELAXED, __HIP_MEMORY_SCOPE_AGENT);
        }
      }
      if (gcol >= 0) gx_lds[((t+1)&1)*32 + (tid & 31)] = gxn;
      __syncthreads();                                     // drains vmcnt -> h' visible
      if (tid == 0) __hip_atomic_store(flagB + (size_t)g*FSTRIDE, t + 1,
                                       __ATOMIC_RELAXED, __HIP_MEMORY_SCOPE_AGENT);
    }
  }
}

// ---------------- out = h_final @ w_out + b_out ----------------------------
__global__ __launch_bounds__(1024) void out_proj(const float* __restrict__ hfin,
                                                 const float* __restrict__ w_out,
                                                 const float* __restrict__ b_out,
                                                 float* __restrict__ out){
  __shared__ float red[16][80];
  const int g  = blockIdx.x;
  const int cl = threadIdx.x & 63;
  const int kc = threadIdx.x >> 6;        // 0..15
  const int col = 64*g + cl;
  float acc = 0.f;
  for (int k = kc*128; k < kc*128 + 128; ++k)
    acc = fmaf(hfin[k], w_out[(size_t)k*EOUT + col], acc);
  red[kc][cl] = acc;
  __syncthreads();
  if (kc == 0){
    float s = 0.f;
    #pragma unroll
    for (int q = 0; q < 16; ++q) s += red[q][cl];
    out[col] = s + b_out[col];
  }
}

extern "C" void kernel_launch(void* const* d_in, const int* in_sizes, int n_in,
                              void* d_out, int out_size, void* d_ws, size_t ws_size,
                              hipStream_t stream) {
  const float* x     = (const float*)d_in[0];   // (8192, 2048)
  const float* w_i   = (const float*)d_in[1];   // (2048, 6144)
  const float* w_h   = (const float*)d_in[2];   // (2048, 6144)
  const float* b     = (const float*)d_in[3];   // (6144,)
  const float* w_out = (const float*)d_in[4];   // (2048, 512)
  const float* b_out = (const float*)d_in[5];   // (512,)
  float* out = (float*)d_out;

  // Workspace layout: gates f32 (201.3MB) | hbuf[2][2048] | rhbuf[2][2048]
  //                   | flagA[64*32] | flagB[128*32]   (flags padded to 128B)
  float* gates = (float*)d_ws;
  float* hbuf  = gates + (size_t)T_STEPS * G3;
  float* rhbuf = hbuf + 2*HD;
  int*   flagA = (int*)(rhbuf + 2*HD);
  int*   flagB = flagA + NA*FSTRIDE;
  (void)in_sizes; (void)n_in; (void)out_size; (void)ws_size;

  // zero h0 + rh + flags (in-stream, graph-capturable)
  hipMemsetAsync(hbuf, 0,
                 (size_t)(2*HD + 2*HD)*sizeof(float) + (size_t)(NA + NB)*FSTRIDE*sizeof(int),
                 stream);

  gates_gemm<<<dim3((T_STEPS/128)*(G3/128)), dim3(256), 0, stream>>>(x, w_i, gates);

  const float* gates_c = gates;
  void* kargs[7];
  kargs[0] = (void*)&gates_c;
  kargs[1] = (void*)&w_h;
  kargs[2] = (void*)&b;
  kargs[3] = (void*)&hbuf;
  kargs[4] = (void*)&rhbuf;
  kargs[5] = (void*)&flagA;
  kargs[6] = (void*)&flagB;
  hipLaunchCooperativeKernel((void*)scan_kernel, dim3(NA + NB), dim3(512), kargs, 0u, stream);

  // T even -> final h in hbuf[0]
  out_proj<<<dim3(EOUT/64), dim3(1024), 0, stream>>>(hbuf, w_out, b_out, out);
}